// Round 17
// baseline (140.916 us; speedup 1.0000x reference)
//
#include <hip/hip_runtime.h>
#include <hip/hip_fp16.h>
#include <math.h>

#define N_NODES  50000
#define N_EDGES  800000
#define IN_DIM   64
#define HID_DIM  64
#define N_CLS    10
#define NBUCK    196      // ceil(N_NODES/256) coarse buckets (dst >> 8)
#define PBLK     256      // partition chunks/blocks
#define PCHUNK   (N_EDGES / PBLK)   // 3125 edges per chunk (exact)
#define FCAP     8192     // k_fine LDS edge cache capacity (32 KB)
#define CSTRIDE  8192     // fixed csr slots per bucket (max bucket ~5.3k incl pads)
#define ZROW     50000    // zero-row index for pad gathers

// unpack 4 fp16 (carried in a float2) to float4
__device__ __forceinline__ float4 h4_to_f4(float2 raw) {
    union { float2 f; __half2 h[2]; } u;
    u.f = raw;
    float2 lo = __half22float2(u.h[0]);
    float2 hi = __half22float2(u.h[1]);
    return make_float4(lo.x, lo.y, hi.x, hi.y);
}

// ---------------- pass 1a: per-chunk coarse histogram (dst>>8), 256 blocks ----------------
__global__ __launch_bounds__(256) void k_chist(const int* __restrict__ dst,
                                               int* __restrict__ bhist) {
    __shared__ int lh[NBUCK];
    int t = threadIdx.x;
    for (int i = t; i < NBUCK; i += 256) lh[i] = 0;
    __syncthreads();
    int beg = blockIdx.x * PCHUNK, end = beg + PCHUNK;
    for (int e = beg + t; e < end; e += 256)
        atomicAdd(&lh[dst[e] >> 8], 1);          // LDS atomic
    __syncthreads();
    for (int i = t; i < NBUCK; i += 256)
        bhist[i * PBLK + blockIdx.x] = lh[i];    // bin-major
}

// ---------------- pass 1b: per-bin exclusive scan over the 256 chunk counts ----------------
__global__ __launch_bounds__(256) void k_scan2(int* __restrict__ bhist,
                                               int* __restrict__ bintot) {
    __shared__ int s[256];
    int t = threadIdx.x;
    int bin = blockIdx.x;
    int c = bhist[bin * PBLK + t];
    s[t] = c;
    __syncthreads();
    for (int d = 1; d < 256; d <<= 1) {
        int v = (t >= d) ? s[t - d] : 0;
        __syncthreads();
        if (t >= d) s[t] += v;
        __syncthreads();
    }
    bhist[bin * PBLK + t] = s[t] - c;            // exclusive within-bin
    if (t == 255) bintot[bin] = s[255];          // bin total
}

// ---------------- pass 1c: scan 196 bin totals -> bbase; zero the ZROW pads ----------------
__global__ __launch_bounds__(256) void k_bscan(const int* __restrict__ bintot,
                                               int* __restrict__ bbase,
                                               float2* __restrict__ xlh,
                                               __half* __restrict__ hlh) {
    __shared__ int s[256];
    int t = threadIdx.x;
    int v = (t < NBUCK) ? bintot[t] : 0;
    s[t] = v;
    __syncthreads();
    for (int d = 1; d < 256; d <<= 1) {
        int u = (t >= d) ? s[t - d] : 0;
        __syncthreads();
        if (t >= d) s[t] += u;
        __syncthreads();
    }
    if (t < NBUCK) bbase[t] = s[t] - v;          // exclusive
    if (t == 0) bbase[NBUCK] = N_EDGES;
    // zero rows consumed by pad gathers
    if (t < 16) xlh[(size_t)ZROW * 16 + t] = make_float2(0.f, 0.f);
    if (t >= 16 && t < 26) hlh[(size_t)ZROW * N_CLS + (t - 16)] = __float2half(0.f);
}

// ---------------- pass 1d: partition edges into coarse buckets (packed), 256 blocks ----------------
__global__ __launch_bounds__(256) void k_partition(const int* __restrict__ src,
                                                   const int* __restrict__ dst,
                                                   const int* __restrict__ bhist,
                                                   const int* __restrict__ bbase,
                                                   int* __restrict__ packed) {
    __shared__ int cur[NBUCK];
    int t = threadIdx.x;
    for (int i = t; i < NBUCK; i += 256)
        cur[i] = bbase[i] + bhist[i * PBLK + blockIdx.x];
    __syncthreads();
    int beg = blockIdx.x * PCHUNK, end = beg + PCHUNK;
    for (int e = beg + t; e < end; e += 256) {
        int d = dst[e], sv = src[e];
        int slot = atomicAdd(&cur[d >> 8], 1);          // LDS atomic
        packed[slot] = ((d & 255) << 16) | sv;          // run-contiguous per (blk,bin)
    }
}

// ---------------- pass 2: per-bucket fine CSR (padded to x4) + off/nend + dinv ----------------
// csr region for bucket b is fixed: [b*CSTRIDE, (b+1)*CSTRIDE). Pad slots -> ZROW.
__global__ __launch_bounds__(1024) void k_fine(const int* __restrict__ packed,
                                               const int* __restrict__ bbase,
                                               int* __restrict__ off,
                                               int* __restrict__ nend,
                                               float* __restrict__ dinv,
                                               int* __restrict__ csr) {
    __shared__ int hist[256];
    __shared__ int scan[256];
    __shared__ int cur[256];
    __shared__ int ecache[FCAP];            // 32 KB
    int t = threadIdx.x;
    int bucket = blockIdx.x;
    if (t < 256) hist[t] = 0;
    __syncthreads();
    int beg = bbase[bucket], end = bbase[bucket + 1];
    int ne = end - beg;
    bool cached = ne <= FCAP;
    if (cached) {
        for (int i = t; i < ne; i += 1024) {
            int p = packed[beg + i];
            ecache[i] = p;
            atomicAdd(&hist[p >> 16], 1);
        }
    } else {
        for (int i = beg + t; i < end; i += 1024)
            atomicAdd(&hist[packed[i] >> 16], 1);
    }
    __syncthreads();
    int padded = (t < 256) ? ((hist[t] + 3) & ~3) : 0;
    if (t < 256) scan[t] = padded;
    __syncthreads();
    for (int d = 1; d < 256; d <<= 1) {
        int v = 0;
        if (t < 256 && t >= d) v = scan[t - d];
        __syncthreads();
        if (t < 256 && t >= d) scan[t] += v;
        __syncthreads();
    }
    int base = bucket * CSTRIDE;
    if (t < 256) {
        int o = base + scan[t] - padded;             // exclusive padded prefix
        cur[t] = o;
        int node = bucket * 256 + t;
        if (node < N_NODES) {
            off[node]  = o;
            nend[node] = o + padded;
            dinv[node] = rsqrtf((float)(hist[t] + 1));   // +1 self-loop
        }
    }
    __syncthreads();
    if (cached) {
        for (int i = t; i < ne; i += 1024) {
            int p = ecache[i];
            int slot = atomicAdd(&cur[p >> 16], 1);      // LDS atomic
            csr[slot] = p & 0xFFFF;
        }
    } else {
        for (int i = beg + t; i < end; i += 1024) {
            int p = packed[i];
            int slot = atomicAdd(&cur[p >> 16], 1);
            csr[slot] = p & 0xFFFF;
        }
    }
    __syncthreads();
    if (t < 256) {
        int node = bucket * 256 + t;
        if (node < N_NODES) {
            int e2 = nend[node];
            for (int i = cur[t]; i < e2; ++i) csr[i] = ZROW;   // <=3 pad fills
        }
    }
}

// ---------------- xl' = fp16((x @ W1) * dinv[row]) — 16-row tile, all-LDS inner loop ----------------
__global__ __launch_bounds__(256) void k_xw64(const float* __restrict__ x,
                                              const float* __restrict__ W,
                                              const float* __restrict__ dinv,
                                              float2* __restrict__ out /* fp16x4 */) {
    __shared__ float4 sW4[IN_DIM * 16];   // W1: 64 rows x 16 col-quads (16 KB)
    __shared__ float4 sx4[16 * 16];       // x tile: 16 rows x 16 k-quads (4 KB)
    int tid = threadIdx.x;
    const float4* W4 = (const float4*)W;
#pragma unroll
    for (int i = 0; i < 4; ++i) sW4[tid + 256 * i] = W4[tid + 256 * i];
    int rowbase = blockIdx.x * 16;
    sx4[tid] = ((const float4*)(x + (size_t)rowbase * IN_DIM))[tid];  // coalesced
    __syncthreads();
    int r  = tid >> 4;     // row in tile
    int cq = tid & 15;     // col quad
    const float4* sxr = &sx4[r * 16];
    float ax = 0.0f, ay = 0.0f, az = 0.0f, aw = 0.0f;
#pragma unroll
    for (int k4 = 0; k4 < 16; ++k4) {
        float4 xv = sxr[k4];
        float4 w0 = sW4[(k4 * 4 + 0) * 16 + cq];
        float4 w1 = sW4[(k4 * 4 + 1) * 16 + cq];
        float4 w2 = sW4[(k4 * 4 + 2) * 16 + cq];
        float4 w3 = sW4[(k4 * 4 + 3) * 16 + cq];
        ax += xv.x * w0.x + xv.y * w1.x + xv.z * w2.x + xv.w * w3.x;
        ay += xv.x * w0.y + xv.y * w1.y + xv.z * w2.y + xv.w * w3.y;
        az += xv.x * w0.z + xv.y * w1.z + xv.z * w2.z + xv.w * w3.z;
        aw += xv.x * w0.w + xv.y * w1.w + xv.z * w2.w + xv.w * w3.w;
    }
    int row = rowbase + r;
    float dv = dinv[row];
    union { __half2 h[2]; float2 f; } u;
    u.h[0] = __floats2half2_rn(ax * dv, ay * dv);
    u.h[1] = __floats2half2_rn(az * dv, aw * dv);
    out[(size_t)row * 16 + cq] = u.f;
}

// ---------------- fused layer-1 gather + relu + (h@W2)*dinv -> fp16 hl' ----------------
// 16 lanes per node (4 dims each); 16 gathers in flight per main-loop iteration.
__global__ __launch_bounds__(256) void k_gather64(const float2* __restrict__ xlph,
                                                  const int* __restrict__ csr,
                                                  const int* __restrict__ off,
                                                  const int* __restrict__ nend,
                                                  const float* __restrict__ dinv,
                                                  const float* __restrict__ b1,
                                                  const float* __restrict__ W2,
                                                  __half* __restrict__ hlh /* stride 10 */) {
    __shared__ float sW2[HID_DIM][N_CLS + 1];   // pad 11 -> 2-way bank alias (free)
    int tid = threadIdx.x;
    for (int i = tid; i < HID_DIM * N_CLS; i += 256)
        sW2[i / N_CLS][i - (i / N_CLS) * N_CLS] = W2[i];
    __syncthreads();
    int node = blockIdx.x * 16 + (tid >> 4);   // 50000 = 16*3125 exact
    int d4 = tid & 15;
    int beg = off[node], end = nend[node];
    float4 acc = h4_to_f4(xlph[(size_t)node * 16 + d4]);   // self-loop (dinv folded in)
    int j = beg;
    for (; j + 16 <= end; j += 16) {                   // 4 int4 index loads + 16 gathers in flight
        int4 c0 = *(const int4*)(csr + j);
        int4 c1 = *(const int4*)(csr + j + 4);
        int4 c2 = *(const int4*)(csr + j + 8);
        int4 c3 = *(const int4*)(csr + j + 12);
        float2 r0 = xlph[(size_t)c0.x * 16 + d4];
        float2 r1 = xlph[(size_t)c0.y * 16 + d4];
        float2 r2 = xlph[(size_t)c0.z * 16 + d4];
        float2 r3 = xlph[(size_t)c0.w * 16 + d4];
        float2 r4 = xlph[(size_t)c1.x * 16 + d4];
        float2 r5 = xlph[(size_t)c1.y * 16 + d4];
        float2 r6 = xlph[(size_t)c1.z * 16 + d4];
        float2 r7 = xlph[(size_t)c1.w * 16 + d4];
        float2 r8 = xlph[(size_t)c2.x * 16 + d4];
        float2 r9 = xlph[(size_t)c2.y * 16 + d4];
        float2 ra = xlph[(size_t)c2.z * 16 + d4];
        float2 rb = xlph[(size_t)c2.w * 16 + d4];
        float2 rc = xlph[(size_t)c3.x * 16 + d4];
        float2 rd = xlph[(size_t)c3.y * 16 + d4];
        float2 re = xlph[(size_t)c3.z * 16 + d4];
        float2 rf = xlph[(size_t)c3.w * 16 + d4];
        float4 v0 = h4_to_f4(r0), v1 = h4_to_f4(r1);
        float4 v2 = h4_to_f4(r2), v3 = h4_to_f4(r3);
        float4 v4 = h4_to_f4(r4), v5 = h4_to_f4(r5);
        float4 v6 = h4_to_f4(r6), v7 = h4_to_f4(r7);
        float4 v8 = h4_to_f4(r8), v9 = h4_to_f4(r9);
        float4 va = h4_to_f4(ra), vb = h4_to_f4(rb);
        float4 vc = h4_to_f4(rc), vd = h4_to_f4(rd);
        float4 ve = h4_to_f4(re), vf = h4_to_f4(rf);
        acc.x += (((v0.x + v1.x) + (v2.x + v3.x)) + ((v4.x + v5.x) + (v6.x + v7.x)))
               + (((v8.x + v9.x) + (va.x + vb.x)) + ((vc.x + vd.x) + (ve.x + vf.x)));
        acc.y += (((v0.y + v1.y) + (v2.y + v3.y)) + ((v4.y + v5.y) + (v6.y + v7.y)))
               + (((v8.y + v9.y) + (va.y + vb.y)) + ((vc.y + vd.y) + (ve.y + vf.y)));
        acc.z += (((v0.z + v1.z) + (v2.z + v3.z)) + ((v4.z + v5.z) + (v6.z + v7.z)))
               + (((v8.z + v9.z) + (va.z + vb.z)) + ((vc.z + vd.z) + (ve.z + vf.z)));
        acc.w += (((v0.w + v1.w) + (v2.w + v3.w)) + ((v4.w + v5.w) + (v6.w + v7.w)))
               + (((v8.w + v9.w) + (va.w + vb.w)) + ((vc.w + vd.w) + (ve.w + vf.w)));
    }
    for (; j < end; j += 4) {                          // padded 4-blocks (0..3 iterations)
        int4 c0 = *(const int4*)(csr + j);
        float4 v0 = h4_to_f4(xlph[(size_t)c0.x * 16 + d4]);
        float4 v1 = h4_to_f4(xlph[(size_t)c0.y * 16 + d4]);
        float4 v2 = h4_to_f4(xlph[(size_t)c0.z * 16 + d4]);
        float4 v3 = h4_to_f4(xlph[(size_t)c0.w * 16 + d4]);
        acc.x += (v0.x + v1.x) + (v2.x + v3.x);
        acc.y += (v0.y + v1.y) + (v2.y + v3.y);
        acc.z += (v0.z + v1.z) + (v2.z + v3.z);
        acc.w += (v0.w + v1.w) + (v2.w + v3.w);
    }
    float dv = dinv[node];
    float4 bb = ((const float4*)b1)[d4];
    float hx = fmaxf(dv * acc.x + bb.x, 0.0f);   // h[4*d4+0..3] in registers
    float hy = fmaxf(dv * acc.y + bb.y, 0.0f);
    float hz = fmaxf(dv * acc.z + bb.z, 0.0f);
    float hw = fmaxf(dv * acc.w + bb.w, 0.0f);
    float p[N_CLS];
    int k0 = d4 * 4;
#pragma unroll
    for (int c = 0; c < N_CLS; ++c)
        p[c] = hx * sW2[k0 + 0][c] + hy * sW2[k0 + 1][c]
             + hz * sW2[k0 + 2][c] + hw * sW2[k0 + 3][c];
#pragma unroll
    for (int k = 1; k < 16; k <<= 1) {
#pragma unroll
        for (int c = 0; c < N_CLS; ++c) p[c] += __shfl_xor(p[c], k, 64);
    }
    if (d4 < N_CLS) {
        float vsel = p[0];
#pragma unroll
        for (int c = 1; c < N_CLS; ++c) vsel = (d4 == c) ? p[c] : vsel;
        hlh[(size_t)node * N_CLS + d4] = __float2half(vsel * dv);
    }
}

// ---------------- layer-2 gather (fp16 hl) + b2 + log_softmax, 16-lane group per node ----------------
__global__ __launch_bounds__(256) void k_gather10(const __half* __restrict__ hlh,
                                                  const int* __restrict__ csr,
                                                  const int* __restrict__ off,
                                                  const int* __restrict__ nend,
                                                  const float* __restrict__ dinv,
                                                  const float* __restrict__ b2,
                                                  float* __restrict__ out) {
    int t = threadIdx.x;
    int node = blockIdx.x * 16 + (t >> 4);
    int d = t & 15;
    bool act = d < N_CLS;
    int dd = act ? d : 0;
    int beg = off[node], end = nend[node];
    float acc = act ? __half2float(hlh[(size_t)node * N_CLS + d]) : 0.0f;
    int j = beg;
    for (; j + 16 <= end; j += 16) {                   // 16 gathers in flight
        int4 c0 = *(const int4*)(csr + j);
        int4 c1 = *(const int4*)(csr + j + 4);
        int4 c2 = *(const int4*)(csr + j + 8);
        int4 c3 = *(const int4*)(csr + j + 12);
        float v0 = __half2float(hlh[(size_t)c0.x * N_CLS + dd]);
        float v1 = __half2float(hlh[(size_t)c0.y * N_CLS + dd]);
        float v2 = __half2float(hlh[(size_t)c0.z * N_CLS + dd]);
        float v3 = __half2float(hlh[(size_t)c0.w * N_CLS + dd]);
        float v4 = __half2float(hlh[(size_t)c1.x * N_CLS + dd]);
        float v5 = __half2float(hlh[(size_t)c1.y * N_CLS + dd]);
        float v6 = __half2float(hlh[(size_t)c1.z * N_CLS + dd]);
        float v7 = __half2float(hlh[(size_t)c1.w * N_CLS + dd]);
        float v8 = __half2float(hlh[(size_t)c2.x * N_CLS + dd]);
        float v9 = __half2float(hlh[(size_t)c2.y * N_CLS + dd]);
        float va = __half2float(hlh[(size_t)c2.z * N_CLS + dd]);
        float vb = __half2float(hlh[(size_t)c2.w * N_CLS + dd]);
        float vc = __half2float(hlh[(size_t)c3.x * N_CLS + dd]);
        float vd = __half2float(hlh[(size_t)c3.y * N_CLS + dd]);
        float ve = __half2float(hlh[(size_t)c3.z * N_CLS + dd]);
        float vf = __half2float(hlh[(size_t)c3.w * N_CLS + dd]);
        if (act) acc += ((((v0 + v1) + (v2 + v3)) + ((v4 + v5) + (v6 + v7)))
                       + (((v8 + v9) + (va + vb)) + ((vc + vd) + (ve + vf))));
    }
    for (; j < end; j += 4) {
        int4 c0 = *(const int4*)(csr + j);
        float v0 = __half2float(hlh[(size_t)c0.x * N_CLS + dd]);
        float v1 = __half2float(hlh[(size_t)c0.y * N_CLS + dd]);
        float v2 = __half2float(hlh[(size_t)c0.z * N_CLS + dd]);
        float v3 = __half2float(hlh[(size_t)c0.w * N_CLS + dd]);
        if (act) acc += (v0 + v1) + (v2 + v3);
    }
    float v = act ? dinv[node] * acc + b2[d] : -INFINITY;
    float m = v;
#pragma unroll
    for (int k = 1; k < 16; k <<= 1) m = fmaxf(m, __shfl_xor(m, k, 64));
    float ex = act ? expf(v - m) : 0.0f;
    float ssum = ex;
#pragma unroll
    for (int k = 1; k < 16; k <<= 1) ssum += __shfl_xor(ssum, k, 64);
    if (act) out[(size_t)node * N_CLS + d] = v - m - logf(ssum);
}

extern "C" void kernel_launch(void* const* d_in, const int* in_sizes, int n_in,
                              void* d_out, int out_size, void* d_ws, size_t ws_size,
                              hipStream_t stream) {
    const float* x  = (const float*)d_in[0];
    const int*   ei = (const int*)d_in[1];
    const float* W1 = (const float*)d_in[2];
    const float* b1 = (const float*)d_in[3];
    const float* W2 = (const float*)d_in[4];
    const float* b2 = (const float*)d_in[5];
    float* out = (float*)d_out;

    const int* src = ei;             // edge_index[0]
    const int* dst = ei + N_EDGES;   // edge_index[1]

    // workspace layout (all segment starts 16B-aligned)
    int*    bhist  = (int*)d_ws;                   // 196*256 = 50176 (pad 50432)
    int*    bintot = bhist + 50432;                // 196 (pad 256)
    int*    bbase  = bintot + 256;                 // 197 (pad 256)
    int*    off    = bbase + 256;                  // 50000 (pad 50048)
    int*    nend   = off + 50048;                  // 50000 (pad 50048)
    int*    packed = nend + 50048;                 // 800000
    int*    csr    = packed + N_EDGES;             // 196*8192 = 1605632 (6.4 MB)
    float*  dinv   = (float*)(csr + NBUCK * CSTRIDE); // 50000 (pad 50048)
    float2* xlh    = (float2*)(dinv + 50048);      // fp16 xl': 50001 rows x 16 float2
    __half* hlh    = (__half*)(xlh + (size_t)(N_NODES + 1) * 16);  // fp16 hl': 50001 x 10

    const int B = 256;
    int g_x64 = N_NODES / 16;                     // 3125 exact
    int g_g16 = N_NODES / 16;                     // 3125 exact

    k_chist    <<<PBLK,  B, 0, stream>>>(dst, bhist);
    k_scan2    <<<NBUCK, B, 0, stream>>>(bhist, bintot);
    k_bscan    <<<1,     B, 0, stream>>>(bintot, bbase, xlh, hlh);
    k_partition<<<PBLK,  B, 0, stream>>>(src, dst, bhist, bbase, packed);
    k_fine     <<<NBUCK, 1024, 0, stream>>>(packed, bbase, off, nend, dinv, csr);
    k_xw64     <<<g_x64,   B, 0, stream>>>(x, W1, dinv, xlh);
    k_gather64 <<<g_g16,   B, 0, stream>>>(xlh, csr, off, nend, dinv, b1, W2, hlh);
    k_gather10 <<<g_g16,   B, 0, stream>>>(hlh, csr, off, nend, dinv, b2, out);
    (void)in_sizes; (void)n_in; (void)out_size; (void)ws_size;
}

// Round 18
// 138.921 us; speedup vs baseline: 1.0144x; 1.0144x over previous
//
#include <hip/hip_runtime.h>
#include <hip/hip_fp16.h>
#include <math.h>

#define N_NODES  50000
#define N_EDGES  800000
#define IN_DIM   64
#define HID_DIM  64
#define N_CLS    10
#define NBUCK    196      // ceil(N_NODES/256) coarse buckets (dst >> 8)
#define PBLK     256      // partition chunks/blocks
#define PCHUNK   (N_EDGES / PBLK)   // 3125 edges per chunk (exact)
#define FCAP     8192     // k_fine LDS edge cache capacity (32 KB)
#define CSTRIDE  8192     // fixed csr slots per bucket (max bucket ~5.3k incl pads)
#define ZROW     50000    // zero-row index for pad gathers

// unpack 4 fp16 (carried in a float2) to float4
__device__ __forceinline__ float4 h4_to_f4(float2 raw) {
    union { float2 f; __half2 h[2]; } u;
    u.f = raw;
    float2 lo = __half22float2(u.h[0]);
    float2 hi = __half22float2(u.h[1]);
    return make_float4(lo.x, lo.y, hi.x, hi.y);
}

// ---------------- pass 1a: per-chunk coarse histogram (dst>>8), 256 blocks ----------------
__global__ __launch_bounds__(256) void k_chist(const int* __restrict__ dst,
                                               int* __restrict__ bhist) {
    __shared__ int lh[NBUCK];
    int t = threadIdx.x;
    for (int i = t; i < NBUCK; i += 256) lh[i] = 0;
    __syncthreads();
    int beg = blockIdx.x * PCHUNK, end = beg + PCHUNK;
    for (int e = beg + t; e < end; e += 256)
        atomicAdd(&lh[dst[e] >> 8], 1);          // LDS atomic
    __syncthreads();
    for (int i = t; i < NBUCK; i += 256)
        bhist[i * PBLK + blockIdx.x] = lh[i];    // bin-major
}

// ---------------- pass 1b: per-bin exclusive scan over the 256 chunk counts ----------------
// also zeroes the ZROW pad rows (block 0).
__global__ __launch_bounds__(256) void k_scan2(int* __restrict__ bhist,
                                               int* __restrict__ bintot,
                                               float2* __restrict__ xlh,
                                               __half* __restrict__ hlh) {
    __shared__ int s[256];
    int t = threadIdx.x;
    int bin = blockIdx.x;
    int c = bhist[bin * PBLK + t];
    s[t] = c;
    __syncthreads();
    for (int d = 1; d < 256; d <<= 1) {
        int v = (t >= d) ? s[t - d] : 0;
        __syncthreads();
        if (t >= d) s[t] += v;
        __syncthreads();
    }
    bhist[bin * PBLK + t] = s[t] - c;            // exclusive within-bin
    if (t == 255) bintot[bin] = s[255];          // bin total
    if (bin == 0) {                              // zero rows consumed by pad gathers
        if (t < 16) xlh[(size_t)ZROW * 16 + t] = make_float2(0.f, 0.f);
        if (t >= 16 && t < 26) hlh[(size_t)ZROW * N_CLS + (t - 16)] = __float2half(0.f);
    }
}

// ---------------- pass 1c: partition edges into coarse buckets (packed), 256 blocks ----------------
// computes the 196-bin global prefix locally in LDS (replaces k_bscan).
__global__ __launch_bounds__(256) void k_partition(const int* __restrict__ src,
                                                   const int* __restrict__ dst,
                                                   const int* __restrict__ bhist,
                                                   const int* __restrict__ bintot,
                                                   int* __restrict__ packed) {
    __shared__ int sbase[256];
    __shared__ int cur[NBUCK];
    int t = threadIdx.x;
    int v = (t < NBUCK) ? bintot[t] : 0;
    sbase[t] = v;
    __syncthreads();
    for (int d = 1; d < 256; d <<= 1) {
        int u = (t >= d) ? sbase[t - d] : 0;
        __syncthreads();
        if (t >= d) sbase[t] += u;
        __syncthreads();
    }
    if (t < NBUCK)
        cur[t] = (sbase[t] - v) + bhist[t * PBLK + blockIdx.x];   // bbase + within-bin off
    __syncthreads();
    int beg = blockIdx.x * PCHUNK, end = beg + PCHUNK;
    for (int e = beg + t; e < end; e += 256) {
        int d = dst[e], sv = src[e];
        int slot = atomicAdd(&cur[d >> 8], 1);          // LDS atomic
        packed[slot] = ((d & 255) << 16) | sv;          // run-contiguous per (blk,bin)
    }
}

// ---------------- pass 2: per-bucket fine CSR (padded to x4) + off/nend + dinv ----------------
// csr region for bucket b is fixed: [b*CSTRIDE, (b+1)*CSTRIDE). Pad slots -> ZROW.
// computes its own bucket base from bintot (replaces k_bscan).
__global__ __launch_bounds__(1024) void k_fine(const int* __restrict__ packed,
                                               const int* __restrict__ bintot,
                                               int* __restrict__ off,
                                               int* __restrict__ nend,
                                               float* __restrict__ dinv,
                                               int* __restrict__ csr) {
    __shared__ int sbase[256];
    __shared__ int hist[256];
    __shared__ int scan[256];
    __shared__ int cur[256];
    __shared__ int ecache[FCAP];            // 32 KB
    int t = threadIdx.x;
    int bucket = blockIdx.x;
    // local prefix over bintot -> this bucket's packed range
    if (t < 256) {
        sbase[t] = (t < NBUCK) ? bintot[t] : 0;
        hist[t] = 0;
    }
    __syncthreads();
    for (int d = 1; d < 256; d <<= 1) {
        int u = 0;
        if (t < 256 && t >= d) u = sbase[t - d];
        __syncthreads();
        if (t < 256 && t >= d) sbase[t] += u;
        __syncthreads();
    }
    int ne  = bintot[bucket];
    int beg = sbase[bucket] - ne;                // exclusive prefix
    int end = beg + ne;
    bool cached = ne <= FCAP;
    if (cached) {
        for (int i = t; i < ne; i += 1024) {
            int p = packed[beg + i];
            ecache[i] = p;
            atomicAdd(&hist[p >> 16], 1);
        }
    } else {
        for (int i = beg + t; i < end; i += 1024)
            atomicAdd(&hist[packed[i] >> 16], 1);
    }
    __syncthreads();
    int padded = (t < 256) ? ((hist[t] + 3) & ~3) : 0;
    if (t < 256) scan[t] = padded;
    __syncthreads();
    for (int d = 1; d < 256; d <<= 1) {
        int v = 0;
        if (t < 256 && t >= d) v = scan[t - d];
        __syncthreads();
        if (t < 256 && t >= d) scan[t] += v;
        __syncthreads();
    }
    int base = bucket * CSTRIDE;
    if (t < 256) {
        int o = base + scan[t] - padded;             // exclusive padded prefix
        cur[t] = o;
        int node = bucket * 256 + t;
        if (node < N_NODES) {
            off[node]  = o;
            nend[node] = o + padded;
            dinv[node] = rsqrtf((float)(hist[t] + 1));   // +1 self-loop
        }
    }
    __syncthreads();
    if (cached) {
        for (int i = t; i < ne; i += 1024) {
            int p = ecache[i];
            int slot = atomicAdd(&cur[p >> 16], 1);      // LDS atomic
            csr[slot] = p & 0xFFFF;
        }
    } else {
        for (int i = beg + t; i < end; i += 1024) {
            int p = packed[i];
            int slot = atomicAdd(&cur[p >> 16], 1);
            csr[slot] = p & 0xFFFF;
        }
    }
    __syncthreads();
    if (t < 256) {
        int node = bucket * 256 + t;
        if (node < N_NODES) {
            int e2 = nend[node];
            for (int i = cur[t]; i < e2; ++i) csr[i] = ZROW;   // <=3 pad fills
        }
    }
}

// ---------------- xl' = fp16((x @ W1) * dinv[row]) — 16-row tile, all-LDS inner loop ----------------
__global__ __launch_bounds__(256) void k_xw64(const float* __restrict__ x,
                                              const float* __restrict__ W,
                                              const float* __restrict__ dinv,
                                              float2* __restrict__ out /* fp16x4 */) {
    __shared__ float4 sW4[IN_DIM * 16];   // W1: 64 rows x 16 col-quads (16 KB)
    __shared__ float4 sx4[16 * 16];       // x tile: 16 rows x 16 k-quads (4 KB)
    int tid = threadIdx.x;
    const float4* W4 = (const float4*)W;
#pragma unroll
    for (int i = 0; i < 4; ++i) sW4[tid + 256 * i] = W4[tid + 256 * i];
    int rowbase = blockIdx.x * 16;
    sx4[tid] = ((const float4*)(x + (size_t)rowbase * IN_DIM))[tid];  // coalesced
    __syncthreads();
    int r  = tid >> 4;     // row in tile
    int cq = tid & 15;     // col quad
    const float4* sxr = &sx4[r * 16];
    float ax = 0.0f, ay = 0.0f, az = 0.0f, aw = 0.0f;
#pragma unroll
    for (int k4 = 0; k4 < 16; ++k4) {
        float4 xv = sxr[k4];
        float4 w0 = sW4[(k4 * 4 + 0) * 16 + cq];
        float4 w1 = sW4[(k4 * 4 + 1) * 16 + cq];
        float4 w2 = sW4[(k4 * 4 + 2) * 16 + cq];
        float4 w3 = sW4[(k4 * 4 + 3) * 16 + cq];
        ax += xv.x * w0.x + xv.y * w1.x + xv.z * w2.x + xv.w * w3.x;
        ay += xv.x * w0.y + xv.y * w1.y + xv.z * w2.y + xv.w * w3.y;
        az += xv.x * w0.z + xv.y * w1.z + xv.z * w2.z + xv.w * w3.z;
        aw += xv.x * w0.w + xv.y * w1.w + xv.z * w2.w + xv.w * w3.w;
    }
    int row = rowbase + r;
    float dv = dinv[row];
    union { __half2 h[2]; float2 f; } u;
    u.h[0] = __floats2half2_rn(ax * dv, ay * dv);
    u.h[1] = __floats2half2_rn(az * dv, aw * dv);
    out[(size_t)row * 16 + cq] = u.f;
}

// ---------------- fused layer-1 gather + relu + (h@W2)*dinv -> fp16 hl' ----------------
// 16 lanes per node (4 dims each); csr indices loaded as aligned int4; loops branchless.
__global__ __launch_bounds__(256) void k_gather64(const float2* __restrict__ xlph,
                                                  const int* __restrict__ csr,
                                                  const int* __restrict__ off,
                                                  const int* __restrict__ nend,
                                                  const float* __restrict__ dinv,
                                                  const float* __restrict__ b1,
                                                  const float* __restrict__ W2,
                                                  __half* __restrict__ hlh /* stride 10 */) {
    __shared__ float sW2[HID_DIM][N_CLS + 1];   // pad 11 -> 2-way bank alias (free)
    int tid = threadIdx.x;
    for (int i = tid; i < HID_DIM * N_CLS; i += 256)
        sW2[i / N_CLS][i - (i / N_CLS) * N_CLS] = W2[i];
    __syncthreads();
    int node = blockIdx.x * 16 + (tid >> 4);   // 50000 = 16*3125 exact
    int d4 = tid & 15;
    int beg = off[node], end = nend[node];
    float4 acc = h4_to_f4(xlph[(size_t)node * 16 + d4]);   // self-loop (dinv folded in)
    int j = beg;
    for (; j + 8 <= end; j += 8) {                     // 2 int4 index loads + 8 gathers
        int4 c0 = *(const int4*)(csr + j);
        int4 c1 = *(const int4*)(csr + j + 4);
        float2 r0 = xlph[(size_t)c0.x * 16 + d4];
        float2 r1 = xlph[(size_t)c0.y * 16 + d4];
        float2 r2 = xlph[(size_t)c0.z * 16 + d4];
        float2 r3 = xlph[(size_t)c0.w * 16 + d4];
        float2 r4 = xlph[(size_t)c1.x * 16 + d4];
        float2 r5 = xlph[(size_t)c1.y * 16 + d4];
        float2 r6 = xlph[(size_t)c1.z * 16 + d4];
        float2 r7 = xlph[(size_t)c1.w * 16 + d4];
        float4 v0 = h4_to_f4(r0), v1 = h4_to_f4(r1);
        float4 v2 = h4_to_f4(r2), v3 = h4_to_f4(r3);
        float4 v4 = h4_to_f4(r4), v5 = h4_to_f4(r5);
        float4 v6 = h4_to_f4(r6), v7 = h4_to_f4(r7);
        acc.x += ((v0.x + v1.x) + (v2.x + v3.x)) + ((v4.x + v5.x) + (v6.x + v7.x));
        acc.y += ((v0.y + v1.y) + (v2.y + v3.y)) + ((v4.y + v5.y) + (v6.y + v7.y));
        acc.z += ((v0.z + v1.z) + (v2.z + v3.z)) + ((v4.z + v5.z) + (v6.z + v7.z));
        acc.w += ((v0.w + v1.w) + (v2.w + v3.w)) + ((v4.w + v5.w) + (v6.w + v7.w));
    }
    if (j < end) {                                     // exactly one padded 4-block
        int4 c0 = *(const int4*)(csr + j);
        float4 v0 = h4_to_f4(xlph[(size_t)c0.x * 16 + d4]);
        float4 v1 = h4_to_f4(xlph[(size_t)c0.y * 16 + d4]);
        float4 v2 = h4_to_f4(xlph[(size_t)c0.z * 16 + d4]);
        float4 v3 = h4_to_f4(xlph[(size_t)c0.w * 16 + d4]);
        acc.x += (v0.x + v1.x) + (v2.x + v3.x);
        acc.y += (v0.y + v1.y) + (v2.y + v3.y);
        acc.z += (v0.z + v1.z) + (v2.z + v3.z);
        acc.w += (v0.w + v1.w) + (v2.w + v3.w);
    }
    float dv = dinv[node];
    float4 bb = ((const float4*)b1)[d4];
    float hx = fmaxf(dv * acc.x + bb.x, 0.0f);   // h[4*d4+0..3] in registers
    float hy = fmaxf(dv * acc.y + bb.y, 0.0f);
    float hz = fmaxf(dv * acc.z + bb.z, 0.0f);
    float hw = fmaxf(dv * acc.w + bb.w, 0.0f);
    float p[N_CLS];
    int k0 = d4 * 4;
#pragma unroll
    for (int c = 0; c < N_CLS; ++c)
        p[c] = hx * sW2[k0 + 0][c] + hy * sW2[k0 + 1][c]
             + hz * sW2[k0 + 2][c] + hw * sW2[k0 + 3][c];
#pragma unroll
    for (int k = 1; k < 16; k <<= 1) {
#pragma unroll
        for (int c = 0; c < N_CLS; ++c) p[c] += __shfl_xor(p[c], k, 64);
    }
    if (d4 < N_CLS) {
        float vsel = p[0];
#pragma unroll
        for (int c = 1; c < N_CLS; ++c) vsel = (d4 == c) ? p[c] : vsel;
        hlh[(size_t)node * N_CLS + d4] = __float2half(vsel * dv);
    }
}

// ---------------- layer-2 gather (fp16 hl) + b2 + log_softmax, 16-lane group per node ----------------
__global__ __launch_bounds__(256) void k_gather10(const __half* __restrict__ hlh,
                                                  const int* __restrict__ csr,
                                                  const int* __restrict__ off,
                                                  const int* __restrict__ nend,
                                                  const float* __restrict__ dinv,
                                                  const float* __restrict__ b2,
                                                  float* __restrict__ out) {
    int t = threadIdx.x;
    int node = blockIdx.x * 16 + (t >> 4);
    int d = t & 15;
    bool act = d < N_CLS;
    int dd = act ? d : 0;
    int beg = off[node], end = nend[node];
    float acc = act ? __half2float(hlh[(size_t)node * N_CLS + d]) : 0.0f;
    int j = beg;
    for (; j + 8 <= end; j += 8) {
        int4 c0 = *(const int4*)(csr + j);
        int4 c1 = *(const int4*)(csr + j + 4);
        float v0 = __half2float(hlh[(size_t)c0.x * N_CLS + dd]);
        float v1 = __half2float(hlh[(size_t)c0.y * N_CLS + dd]);
        float v2 = __half2float(hlh[(size_t)c0.z * N_CLS + dd]);
        float v3 = __half2float(hlh[(size_t)c0.w * N_CLS + dd]);
        float v4 = __half2float(hlh[(size_t)c1.x * N_CLS + dd]);
        float v5 = __half2float(hlh[(size_t)c1.y * N_CLS + dd]);
        float v6 = __half2float(hlh[(size_t)c1.z * N_CLS + dd]);
        float v7 = __half2float(hlh[(size_t)c1.w * N_CLS + dd]);
        if (act) acc += ((v0 + v1) + (v2 + v3)) + ((v4 + v5) + (v6 + v7));
    }
    if (j < end) {
        int4 c0 = *(const int4*)(csr + j);
        float v0 = __half2float(hlh[(size_t)c0.x * N_CLS + dd]);
        float v1 = __half2float(hlh[(size_t)c0.y * N_CLS + dd]);
        float v2 = __half2float(hlh[(size_t)c0.z * N_CLS + dd]);
        float v3 = __half2float(hlh[(size_t)c0.w * N_CLS + dd]);
        if (act) acc += (v0 + v1) + (v2 + v3);
    }
    float v = act ? dinv[node] * acc + b2[d] : -INFINITY;
    float m = v;
#pragma unroll
    for (int k = 1; k < 16; k <<= 1) m = fmaxf(m, __shfl_xor(m, k, 64));
    float ex = act ? expf(v - m) : 0.0f;
    float ssum = ex;
#pragma unroll
    for (int k = 1; k < 16; k <<= 1) ssum += __shfl_xor(ssum, k, 64);
    if (act) out[(size_t)node * N_CLS + d] = v - m - logf(ssum);
}

extern "C" void kernel_launch(void* const* d_in, const int* in_sizes, int n_in,
                              void* d_out, int out_size, void* d_ws, size_t ws_size,
                              hipStream_t stream) {
    const float* x  = (const float*)d_in[0];
    const int*   ei = (const int*)d_in[1];
    const float* W1 = (const float*)d_in[2];
    const float* b1 = (const float*)d_in[3];
    const float* W2 = (const float*)d_in[4];
    const float* b2 = (const float*)d_in[5];
    float* out = (float*)d_out;

    const int* src = ei;             // edge_index[0]
    const int* dst = ei + N_EDGES;   // edge_index[1]

    // workspace layout (all segment starts 16B-aligned)
    int*    bhist  = (int*)d_ws;                   // 196*256 = 50176 (pad 50432)
    int*    bintot = bhist + 50432;                // 196 (pad 256)
    int*    off    = bintot + 256;                 // 50000 (pad 50048)
    int*    nend   = off + 50048;                  // 50000 (pad 50048)
    int*    packed = nend + 50048;                 // 800000
    int*    csr    = packed + N_EDGES;             // 196*8192 = 1605632 (6.4 MB)
    float*  dinv   = (float*)(csr + NBUCK * CSTRIDE); // 50000 (pad 50048)
    float2* xlh    = (float2*)(dinv + 50048);      // fp16 xl': 50001 rows x 16 float2
    __half* hlh    = (__half*)(xlh + (size_t)(N_NODES + 1) * 16);  // fp16 hl': 50001 x 10

    const int B = 256;
    int g_x64 = N_NODES / 16;                     // 3125 exact
    int g_g16 = N_NODES / 16;                     // 3125 exact

    k_chist    <<<PBLK,  B, 0, stream>>>(dst, bhist);
    k_scan2    <<<NBUCK, B, 0, stream>>>(bhist, bintot, xlh, hlh);
    k_partition<<<PBLK,  B, 0, stream>>>(src, dst, bhist, bintot, packed);
    k_fine     <<<NBUCK, 1024, 0, stream>>>(packed, bintot, off, nend, dinv, csr);
    k_xw64     <<<g_x64,   B, 0, stream>>>(x, W1, dinv, xlh);
    k_gather64 <<<g_g16,   B, 0, stream>>>(xlh, csr, off, nend, dinv, b1, W2, hlh);
    k_gather10 <<<g_g16,   B, 0, stream>>>(hlh, csr, off, nend, dinv, b2, out);
    (void)in_sizes; (void)n_in; (void)out_size; (void)ws_size;
}

// Round 19
// 138.623 us; speedup vs baseline: 1.0165x; 1.0021x over previous
//
#include <hip/hip_runtime.h>
#include <hip/hip_fp16.h>
#include <math.h>

#define N_NODES  50000
#define N_EDGES  800000
#define IN_DIM   64
#define HID_DIM  64
#define N_CLS    10
#define NBUCK    196      // ceil(N_NODES/256) coarse buckets (dst >> 8)
#define PBLK     256      // partition chunks/blocks
#define PCHUNK   (N_EDGES / PBLK)   // 3125 edges per chunk (exact)
#define FCAP     8192     // k_fine LDS edge cache capacity (32 KB)
#define PSTRIDE  8192     // fixed packed slots per bucket
#define CSTRIDE  8192     // fixed csr slots per bucket (max bucket ~5.3k incl pads)
#define ZROW     50000    // zero-row index for pad gathers

// unpack 4 fp16 (carried in a float2) to float4
__device__ __forceinline__ float4 h4_to_f4(float2 raw) {
    union { float2 f; __half2 h[2]; } u;
    u.f = raw;
    float2 lo = __half22float2(u.h[0]);
    float2 hi = __half22float2(u.h[1]);
    return make_float4(lo.x, lo.y, hi.x, hi.y);
}

// ---------------- init: bucket cursors to fixed region bases; zero ZROW pad rows ----------------
__global__ __launch_bounds__(256) void k_init(int* __restrict__ gcur,
                                              float2* __restrict__ xlh,
                                              __half* __restrict__ hlh) {
    int t = threadIdx.x;
    if (t < NBUCK) gcur[t] = t * PSTRIDE;
    if (t < 16) xlh[(size_t)ZROW * 16 + t] = make_float2(0.f, 0.f);
    if (t >= 16 && t < 26) hlh[(size_t)ZROW * N_CLS + (t - 16)] = __float2half(0.f);
}

// ---------------- pass 1: hist + global range reservation + scatter, one kernel ----------------
// 256 blocks x 256 threads; dst cached in LDS (read once); 196 global atomics/block.
__global__ __launch_bounds__(256) void k_part1(const int* __restrict__ src,
                                               const int* __restrict__ dst,
                                               int* __restrict__ gcur,
                                               int* __restrict__ packed) {
    __shared__ int lh[NBUCK];
    __shared__ int cur[NBUCK];
    __shared__ int dcache[PCHUNK];          // 12.5 KB
    int t = threadIdx.x;
    for (int i = t; i < NBUCK; i += 256) lh[i] = 0;
    __syncthreads();
    int beg = blockIdx.x * PCHUNK;
    for (int i = t; i < PCHUNK; i += 256) {
        int d = dst[beg + i];
        dcache[i] = d;
        atomicAdd(&lh[d >> 8], 1);          // LDS atomic
    }
    __syncthreads();
    for (int i = t; i < NBUCK; i += 256)
        cur[i] = atomicAdd(&gcur[i], lh[i]);   // device-scope range reservation
    __syncthreads();
    for (int i = t; i < PCHUNK; i += 256) {
        int d = dcache[i];
        int sv = src[beg + i];
        int slot = atomicAdd(&cur[d >> 8], 1);  // LDS atomic
        packed[slot] = ((d & 255) << 16) | sv;  // into bucket's fixed region
    }
}

// ---------------- pass 2: per-bucket fine CSR (padded to x4) + off/nend + dinv ----------------
// packed region for bucket b: [b*PSTRIDE, gcur[b]). csr region: [b*CSTRIDE, ...). Pads -> ZROW.
__global__ __launch_bounds__(1024) void k_fine(const int* __restrict__ packed,
                                               const int* __restrict__ gcur,
                                               int* __restrict__ off,
                                               int* __restrict__ nend,
                                               float* __restrict__ dinv,
                                               int* __restrict__ csr) {
    __shared__ int hist[256];
    __shared__ int scan[256];
    __shared__ int cur[256];
    __shared__ int ecache[FCAP];            // 32 KB
    int t = threadIdx.x;
    int bucket = blockIdx.x;
    if (t < 256) hist[t] = 0;
    __syncthreads();
    int beg = bucket * PSTRIDE;
    int ne  = gcur[bucket] - beg;
    int end = beg + ne;
    bool cached = ne <= FCAP;
    if (cached) {
        for (int i = t; i < ne; i += 1024) {
            int p = packed[beg + i];
            ecache[i] = p;
            atomicAdd(&hist[p >> 16], 1);
        }
    } else {
        for (int i = beg + t; i < end; i += 1024)
            atomicAdd(&hist[packed[i] >> 16], 1);
    }
    __syncthreads();
    int padded = (t < 256) ? ((hist[t] + 3) & ~3) : 0;
    if (t < 256) scan[t] = padded;
    __syncthreads();
    for (int d = 1; d < 256; d <<= 1) {
        int v = 0;
        if (t < 256 && t >= d) v = scan[t - d];
        __syncthreads();
        if (t < 256 && t >= d) scan[t] += v;
        __syncthreads();
    }
    int base = bucket * CSTRIDE;
    if (t < 256) {
        int o = base + scan[t] - padded;             // exclusive padded prefix
        cur[t] = o;
        int node = bucket * 256 + t;
        if (node < N_NODES) {
            off[node]  = o;
            nend[node] = o + padded;
            dinv[node] = rsqrtf((float)(hist[t] + 1));   // +1 self-loop
        }
    }
    __syncthreads();
    if (cached) {
        for (int i = t; i < ne; i += 1024) {
            int p = ecache[i];
            int slot = atomicAdd(&cur[p >> 16], 1);      // LDS atomic
            csr[slot] = p & 0xFFFF;
        }
    } else {
        for (int i = beg + t; i < end; i += 1024) {
            int p = packed[i];
            int slot = atomicAdd(&cur[p >> 16], 1);
            csr[slot] = p & 0xFFFF;
        }
    }
    __syncthreads();
    if (t < 256) {
        int node = bucket * 256 + t;
        if (node < N_NODES) {
            int e2 = nend[node];
            for (int i = cur[t]; i < e2; ++i) csr[i] = ZROW;   // <=3 pad fills
        }
    }
}

// ---------------- xl' = fp16((x @ W1) * dinv[row]) — 16-row tile, all-LDS inner loop ----------------
__global__ __launch_bounds__(256) void k_xw64(const float* __restrict__ x,
                                              const float* __restrict__ W,
                                              const float* __restrict__ dinv,
                                              float2* __restrict__ out /* fp16x4 */) {
    __shared__ float4 sW4[IN_DIM * 16];   // W1: 64 rows x 16 col-quads (16 KB)
    __shared__ float4 sx4[16 * 16];       // x tile: 16 rows x 16 k-quads (4 KB)
    int tid = threadIdx.x;
    const float4* W4 = (const float4*)W;
#pragma unroll
    for (int i = 0; i < 4; ++i) sW4[tid + 256 * i] = W4[tid + 256 * i];
    int rowbase = blockIdx.x * 16;
    sx4[tid] = ((const float4*)(x + (size_t)rowbase * IN_DIM))[tid];  // coalesced
    __syncthreads();
    int r  = tid >> 4;     // row in tile
    int cq = tid & 15;     // col quad
    const float4* sxr = &sx4[r * 16];
    float ax = 0.0f, ay = 0.0f, az = 0.0f, aw = 0.0f;
#pragma unroll
    for (int k4 = 0; k4 < 16; ++k4) {
        float4 xv = sxr[k4];
        float4 w0 = sW4[(k4 * 4 + 0) * 16 + cq];
        float4 w1 = sW4[(k4 * 4 + 1) * 16 + cq];
        float4 w2 = sW4[(k4 * 4 + 2) * 16 + cq];
        float4 w3 = sW4[(k4 * 4 + 3) * 16 + cq];
        ax += xv.x * w0.x + xv.y * w1.x + xv.z * w2.x + xv.w * w3.x;
        ay += xv.x * w0.y + xv.y * w1.y + xv.z * w2.y + xv.w * w3.y;
        az += xv.x * w0.z + xv.y * w1.z + xv.z * w2.z + xv.w * w3.z;
        aw += xv.x * w0.w + xv.y * w1.w + xv.z * w2.w + xv.w * w3.w;
    }
    int row = rowbase + r;
    float dv = dinv[row];
    union { __half2 h[2]; float2 f; } u;
    u.h[0] = __floats2half2_rn(ax * dv, ay * dv);
    u.h[1] = __floats2half2_rn(az * dv, aw * dv);
    out[(size_t)row * 16 + cq] = u.f;
}

// ---------------- fused layer-1 gather + relu + (h@W2)*dinv -> fp16 hl' ----------------
// 16 lanes per node (4 dims each); csr indices loaded as aligned int4; loops branchless.
__global__ __launch_bounds__(256) void k_gather64(const float2* __restrict__ xlph,
                                                  const int* __restrict__ csr,
                                                  const int* __restrict__ off,
                                                  const int* __restrict__ nend,
                                                  const float* __restrict__ dinv,
                                                  const float* __restrict__ b1,
                                                  const float* __restrict__ W2,
                                                  __half* __restrict__ hlh /* stride 10 */) {
    __shared__ float sW2[HID_DIM][N_CLS + 1];   // pad 11 -> 2-way bank alias (free)
    int tid = threadIdx.x;
    for (int i = tid; i < HID_DIM * N_CLS; i += 256)
        sW2[i / N_CLS][i - (i / N_CLS) * N_CLS] = W2[i];
    __syncthreads();
    int node = blockIdx.x * 16 + (tid >> 4);   // 50000 = 16*3125 exact
    int d4 = tid & 15;
    int beg = off[node], end = nend[node];
    float4 acc = h4_to_f4(xlph[(size_t)node * 16 + d4]);   // self-loop (dinv folded in)
    int j = beg;
    for (; j + 8 <= end; j += 8) {                     // 2 int4 index loads + 8 gathers
        int4 c0 = *(const int4*)(csr + j);
        int4 c1 = *(const int4*)(csr + j + 4);
        float2 r0 = xlph[(size_t)c0.x * 16 + d4];
        float2 r1 = xlph[(size_t)c0.y * 16 + d4];
        float2 r2 = xlph[(size_t)c0.z * 16 + d4];
        float2 r3 = xlph[(size_t)c0.w * 16 + d4];
        float2 r4 = xlph[(size_t)c1.x * 16 + d4];
        float2 r5 = xlph[(size_t)c1.y * 16 + d4];
        float2 r6 = xlph[(size_t)c1.z * 16 + d4];
        float2 r7 = xlph[(size_t)c1.w * 16 + d4];
        float4 v0 = h4_to_f4(r0), v1 = h4_to_f4(r1);
        float4 v2 = h4_to_f4(r2), v3 = h4_to_f4(r3);
        float4 v4 = h4_to_f4(r4), v5 = h4_to_f4(r5);
        float4 v6 = h4_to_f4(r6), v7 = h4_to_f4(r7);
        acc.x += ((v0.x + v1.x) + (v2.x + v3.x)) + ((v4.x + v5.x) + (v6.x + v7.x));
        acc.y += ((v0.y + v1.y) + (v2.y + v3.y)) + ((v4.y + v5.y) + (v6.y + v7.y));
        acc.z += ((v0.z + v1.z) + (v2.z + v3.z)) + ((v4.z + v5.z) + (v6.z + v7.z));
        acc.w += ((v0.w + v1.w) + (v2.w + v3.w)) + ((v4.w + v5.w) + (v6.w + v7.w));
    }
    if (j < end) {                                     // exactly one padded 4-block
        int4 c0 = *(const int4*)(csr + j);
        float4 v0 = h4_to_f4(xlph[(size_t)c0.x * 16 + d4]);
        float4 v1 = h4_to_f4(xlph[(size_t)c0.y * 16 + d4]);
        float4 v2 = h4_to_f4(xlph[(size_t)c0.z * 16 + d4]);
        float4 v3 = h4_to_f4(xlph[(size_t)c0.w * 16 + d4]);
        acc.x += (v0.x + v1.x) + (v2.x + v3.x);
        acc.y += (v0.y + v1.y) + (v2.y + v3.y);
        acc.z += (v0.z + v1.z) + (v2.z + v3.z);
        acc.w += (v0.w + v1.w) + (v2.w + v3.w);
    }
    float dv = dinv[node];
    float4 bb = ((const float4*)b1)[d4];
    float hx = fmaxf(dv * acc.x + bb.x, 0.0f);   // h[4*d4+0..3] in registers
    float hy = fmaxf(dv * acc.y + bb.y, 0.0f);
    float hz = fmaxf(dv * acc.z + bb.z, 0.0f);
    float hw = fmaxf(dv * acc.w + bb.w, 0.0f);
    float p[N_CLS];
    int k0 = d4 * 4;
#pragma unroll
    for (int c = 0; c < N_CLS; ++c)
        p[c] = hx * sW2[k0 + 0][c] + hy * sW2[k0 + 1][c]
             + hz * sW2[k0 + 2][c] + hw * sW2[k0 + 3][c];
#pragma unroll
    for (int k = 1; k < 16; k <<= 1) {
#pragma unroll
        for (int c = 0; c < N_CLS; ++c) p[c] += __shfl_xor(p[c], k, 64);
    }
    if (d4 < N_CLS) {
        float vsel = p[0];
#pragma unroll
        for (int c = 1; c < N_CLS; ++c) vsel = (d4 == c) ? p[c] : vsel;
        hlh[(size_t)node * N_CLS + d4] = __float2half(vsel * dv);
    }
}

// ---------------- layer-2 gather (fp16 hl) + b2 + log_softmax, 16-lane group per node ----------------
__global__ __launch_bounds__(256) void k_gather10(const __half* __restrict__ hlh,
                                                  const int* __restrict__ csr,
                                                  const int* __restrict__ off,
                                                  const int* __restrict__ nend,
                                                  const float* __restrict__ dinv,
                                                  const float* __restrict__ b2,
                                                  float* __restrict__ out) {
    int t = threadIdx.x;
    int node = blockIdx.x * 16 + (t >> 4);
    int d = t & 15;
    bool act = d < N_CLS;
    int dd = act ? d : 0;
    int beg = off[node], end = nend[node];
    float acc = act ? __half2float(hlh[(size_t)node * N_CLS + d]) : 0.0f;
    int j = beg;
    for (; j + 8 <= end; j += 8) {
        int4 c0 = *(const int4*)(csr + j);
        int4 c1 = *(const int4*)(csr + j + 4);
        float v0 = __half2float(hlh[(size_t)c0.x * N_CLS + dd]);
        float v1 = __half2float(hlh[(size_t)c0.y * N_CLS + dd]);
        float v2 = __half2float(hlh[(size_t)c0.z * N_CLS + dd]);
        float v3 = __half2float(hlh[(size_t)c0.w * N_CLS + dd]);
        float v4 = __half2float(hlh[(size_t)c1.x * N_CLS + dd]);
        float v5 = __half2float(hlh[(size_t)c1.y * N_CLS + dd]);
        float v6 = __half2float(hlh[(size_t)c1.z * N_CLS + dd]);
        float v7 = __half2float(hlh[(size_t)c1.w * N_CLS + dd]);
        if (act) acc += ((v0 + v1) + (v2 + v3)) + ((v4 + v5) + (v6 + v7));
    }
    if (j < end) {
        int4 c0 = *(const int4*)(csr + j);
        float v0 = __half2float(hlh[(size_t)c0.x * N_CLS + dd]);
        float v1 = __half2float(hlh[(size_t)c0.y * N_CLS + dd]);
        float v2 = __half2float(hlh[(size_t)c0.z * N_CLS + dd]);
        float v3 = __half2float(hlh[(size_t)c0.w * N_CLS + dd]);
        if (act) acc += (v0 + v1) + (v2 + v3);
    }
    float v = act ? dinv[node] * acc + b2[d] : -INFINITY;
    float m = v;
#pragma unroll
    for (int k = 1; k < 16; k <<= 1) m = fmaxf(m, __shfl_xor(m, k, 64));
    float ex = act ? expf(v - m) : 0.0f;
    float ssum = ex;
#pragma unroll
    for (int k = 1; k < 16; k <<= 1) ssum += __shfl_xor(ssum, k, 64);
    if (act) out[(size_t)node * N_CLS + d] = v - m - logf(ssum);
}

extern "C" void kernel_launch(void* const* d_in, const int* in_sizes, int n_in,
                              void* d_out, int out_size, void* d_ws, size_t ws_size,
                              hipStream_t stream) {
    const float* x  = (const float*)d_in[0];
    const int*   ei = (const int*)d_in[1];
    const float* W1 = (const float*)d_in[2];
    const float* b1 = (const float*)d_in[3];
    const float* W2 = (const float*)d_in[4];
    const float* b2 = (const float*)d_in[5];
    float* out = (float*)d_out;

    const int* src = ei;             // edge_index[0]
    const int* dst = ei + N_EDGES;   // edge_index[1]

    // workspace layout (all segment starts 16B-aligned)
    int*    gcur   = (int*)d_ws;                   // 196 (pad 256)
    int*    off    = gcur + 256;                   // 50000 (pad 50048)
    int*    nend   = off + 50048;                  // 50000 (pad 50048)
    int*    packed = nend + 50048;                 // 196*8192 = 1605632 (6.4 MB)
    int*    csr    = packed + NBUCK * PSTRIDE;     // 196*8192 = 1605632 (6.4 MB)
    float*  dinv   = (float*)(csr + NBUCK * CSTRIDE); // 50000 (pad 50048)
    float2* xlh    = (float2*)(dinv + 50048);      // fp16 xl': 50001 rows x 16 float2
    __half* hlh    = (__half*)(xlh + (size_t)(N_NODES + 1) * 16);  // fp16 hl': 50001 x 10

    const int B = 256;
    int g_x64 = N_NODES / 16;                     // 3125 exact
    int g_g16 = N_NODES / 16;                     // 3125 exact

    k_init    <<<1,     B, 0, stream>>>(gcur, xlh, hlh);
    k_part1   <<<PBLK,  B, 0, stream>>>(src, dst, gcur, packed);
    k_fine    <<<NBUCK, 1024, 0, stream>>>(packed, gcur, off, nend, dinv, csr);
    k_xw64    <<<g_x64,   B, 0, stream>>>(x, W1, dinv, xlh);
    k_gather64<<<g_g16,   B, 0, stream>>>(xlh, csr, off, nend, dinv, b1, W2, hlh);
    k_gather10<<<g_g16,   B, 0, stream>>>(hlh, csr, off, nend, dinv, b2, out);
    (void)in_sizes; (void)n_in; (void)out_size; (void)ws_size;
}